// Round 7
// baseline (496.396 us; speedup 1.0000x reference)
//
#include <hip/hip_runtime.h>

// TensorConvolutionTrainLayer: S=512,P=196,Q=48,CB=8,R=32,C=10,N=8
// R7: 2 samples per block (256 blocks, 1 block/CU, launch_bounds(256,1) ->
// 512-VGPR budget). Both samples' A-slices register-resident (af 224 VGPR,
// no Ash at all); shared Akr B-fragments loaded once per block -> B-L2
// traffic halves vs R6. Gsh double (one per sample); St3/NS/epilogue
// mappings unchanged from R6.

typedef _Float16 half8 __attribute__((ext_vector_type(8)));
typedef _Float16 half4 __attribute__((ext_vector_type(4)));
typedef float floatx4 __attribute__((ext_vector_type(4)));

#define KP 224      // P padded to 7*32
#define QP 64       // Q padded to 2*32
#define GSTR2 72    // Gsh row stride (halfs)
#define SSTR 264    // St3 row stride (halfs)
#define SLICE 14336 // per-(s,k) A slice: 28 frags * 64 lanes * 8 halfs

__device__ __forceinline__ void gld_lds16(const void* g, void* l) {
  __builtin_amdgcn_global_load_lds((const __attribute__((address_space(1))) void*)g,
                                   (__attribute__((address_space(3))) void*)l, 16, 0, 0);
}

// ---------------- generic MFMA GEMM (unchanged from R6) ----------------
template<int K, int MODE>
__global__ __launch_bounds__(256)
void gemm_mfma(const _Float16* __restrict__ A, const _Float16* __restrict__ Bt,
               void* __restrict__ out0, void* __restrict__ out1, void* __restrict__ out2)
{
  __shared__ __align__(16) _Float16 Ash[128 * 32];
  __shared__ __align__(16) _Float16 Bsh[128 * 32];
  const int tid  = threadIdx.x;
  const int wave = tid >> 6;
  const int lane = tid & 63;
  const int m0 = blockIdx.y * 128;
  const int n0 = blockIdx.x * 128;
  const int wm = (wave >> 1) * 64;
  const int wn = (wave & 1) * 64;
  const int fr = lane & 15;
  const int fq = lane >> 4;

  floatx4 acc[4][4] = {};

  for (int kt = 0; kt < K; kt += 32) {
    __syncthreads();
#pragma unroll
    for (int j = 0; j < 2; j++) {
      const int c   = j * 256 + tid;
      const int row = c >> 2;
      const int ko  = (c & 3) * 8;
      gld_lds16(A  + (size_t)(m0 + row) * K + kt + ko,
                (char*)Ash + (size_t)(j * 256 + wave * 64) * 16);
      gld_lds16(Bt + (size_t)(n0 + row) * K + kt + ko,
                (char*)Bsh + (size_t)(j * 256 + wave * 64) * 16);
    }
    __syncthreads();
    half8 af[4], bf[4];
#pragma unroll
    for (int i = 0; i < 4; i++)
      af[i] = *(const half8*)&Ash[(wm + i * 16 + fr) * 32 + fq * 8];
#pragma unroll
    for (int i = 0; i < 4; i++)
      bf[i] = *(const half8*)&Bsh[(wn + i * 16 + fr) * 32 + fq * 8];
#pragma unroll
    for (int i = 0; i < 4; i++)
#pragma unroll
      for (int j = 0; j < 4; j++)
        acc[i][j] = __builtin_amdgcn_mfma_f32_16x16x32_f16(af[i], bf[j], acc[i][j], 0, 0, 0);
  }

#pragma unroll
  for (int i = 0; i < 4; i++) {
#pragma unroll
    for (int j = 0; j < 4; j++) {
#pragma unroll
      for (int r = 0; r < 4; r++) {
        const int m = m0 + wm + i * 16 + fq * 4 + r;
        const int n = n0 + wn + j * 16 + fr;
        const float v = acc[i][j][r];
        if constexpr (MODE == 0) {
          const unsigned s = (unsigned)n / 196u;
          const unsigned p = (unsigned)n - s * 196u;
          if (m < 8) {
            ((_Float16*)out1)[((size_t)m * 512 + s) * KP + p] = (_Float16)v;
          } else if (m < 392) {
            const int mm = m - 8;
            const size_t idx =
              ((((size_t)s * 6 + (mm >> 6)) * 28 + (p >> 5) * 4 + ((mm & 63) >> 4)) * 64
               + ((p >> 3) & 3) * 16 + (mm & 15)) * 8 + (p & 7);
            ((_Float16*)out0)[idx] = (_Float16)v;
          } else if (m < 400) {
            ((_Float16*)out2)[((size_t)(m - 392) * 512 + s) * KP + p] = (_Float16)v;
          }
        } else if constexpr (MODE == 2) {
          if (n < 320)
            ((float*)out0)[(size_t)(m & 511) * 2560 + (m >> 9) * 320 + n] = v;
        } else {
          if (n < 32)
            ((float*)out0)[(size_t)m * 32 + n] = v;
        }
      }
    }
  }
}

// ---------------- fused chain kernel: 2 samples per block ----------------
__global__ __launch_bounds__(256, 1)
void chain_kernel(const _Float16* __restrict__ Mt3, const _Float16* __restrict__ Akr,
                  const float* __restrict__ St0, const float* __restrict__ GN,
                  float* __restrict__ out)
{
  __shared__ __align__(16) _Float16 Gsh[2][256 * GSTR2];  // 73728 B
  __shared__ __align__(16) _Float16 St3[2][16 * SSTR];    // 16896 B
  __shared__ float oc[2][10];

  const int tid  = threadIdx.x;
  const int wave = tid >> 6;
  const int lane = tid & 63;
  const int s0   = blockIdx.x * 2;
  const int fr   = lane & 15;
  const int fq   = lane >> 4;
  const int fqh  = fq >> 1;
  const int fql  = fq & 1;

  // init: St3[sm][c][r*8+sigma(b)] from St0; tid=(b,r)
  {
    const int b = tid >> 5, r = tid & 31;
    const int kcol = r * 8 + ((b & 1) * 4 + (b >> 1));
#pragma unroll
    for (int sm = 0; sm < 2; sm++) {
      const float* src = St0 + (size_t)(s0 + sm) * 2560 + (size_t)tid * 10;
#pragma unroll
      for (int c = 0; c < 10; c++) St3[sm][c * SSTR + kcol] = (_Float16)src[c];
    }
    if (tid < 20) ((float*)oc)[tid] = 0.f;
  }

  // A-slices for step 0, both samples, register-resident (MFMA A-layout)
  half8 af[2][7][4];
#pragma unroll
  for (int sm = 0; sm < 2; sm++) {
    const _Float16* Ab = Mt3 + (size_t)(s0 + sm) * 6 * SLICE;
#pragma unroll
    for (int kt = 0; kt < 7; kt++)
#pragma unroll
      for (int mi = 0; mi < 4; mi++)
        af[sm][kt][mi] = *(const half8*)(Ab + (size_t)((kt * 4 + mi) * 64 + lane) * 8);
  }
  // B fragments for (k=0, cc=0, kt=0)
  half8 bf[2][4];
  {
    const _Float16* Bb = Akr + (size_t)(wave * 64) * KP;
#pragma unroll
    for (int ni = 0; ni < 4; ni++)
      bf[0][ni] = *(const half8*)(Bb + (size_t)(ni * 16 + fr) * KP + fq * 8);
  }
  __syncthreads();   // St3 visible

  for (int k = 0; k < 6; k++) {
    floatx4 ns[2][4] = {};
    const _Float16* Bk = Akr + (size_t)k * 1024 * KP;

    for (int cc = 0; cc < 4; cc++) {
      const _Float16* Bb = Bk + (size_t)(cc * 256 + wave * 64) * KP;
      // ---- G-phase: both samples vs shared bf ----
      floatx4 acc[2][4][4] = {};
#pragma unroll
      for (int kt = 0; kt < 7; kt++) {
        if (kt < 6) {   // rolling prefetch of next kt's B fragments
#pragma unroll
          for (int ni = 0; ni < 4; ni++)
            bf[(kt + 1) & 1][ni] =
              *(const half8*)(Bb + (size_t)(ni * 16 + fr) * KP + (kt + 1) * 32 + fq * 8);
        }
#pragma unroll
        for (int sm = 0; sm < 2; sm++)
#pragma unroll
          for (int mi = 0; mi < 4; mi++)
#pragma unroll
            for (int ni = 0; ni < 4; ni++)
              acc[sm][mi][ni] = __builtin_amdgcn_mfma_f32_16x16x32_f16(
                  af[sm][kt][mi], bf[kt & 1][ni], acc[sm][mi][ni], 0, 0, 0);
      }
      // preload next chunk's kt0 B fragments (covered by cvt+write+barrier+NS)
      if (cc < 3) {
        const _Float16* Bn = Bb + (size_t)256 * KP;
#pragma unroll
        for (int ni = 0; ni < 4; ni++)
          bf[0][ni] = *(const half8*)(Bn + (size_t)(ni * 16 + fr) * KP + fq * 8);
      } else if (k < 5) {
        const _Float16* Bn = Akr + ((size_t)(k + 1) * 1024 + wave * 64) * KP;
#pragma unroll
        for (int ni = 0; ni < 4; ni++)
          bf[0][ni] = *(const half8*)(Bn + (size_t)(ni * 16 + fr) * KP + fq * 8);
      }
      // af's last use this step is cc=3,kt=6: reload next step's slices now
      if (cc == 3 && k < 5) {
#pragma unroll
        for (int sm = 0; sm < 2; sm++) {
          const _Float16* Ab = Mt3 + ((size_t)(s0 + sm) * 6 + k + 1) * SLICE;
#pragma unroll
          for (int kt = 0; kt < 7; kt++)
#pragma unroll
            for (int mi = 0; mi < 4; mi++)
              af[sm][kt][mi] = *(const half8*)(Ab + (size_t)((kt * 4 + mi) * 64 + lane) * 8);
        }
      }
      // cvt + write Gsh for both samples: row m2=(b,r), k' = wave*16+(ni>>1)*8+fqh*4+mi
#pragma unroll
      for (int sm = 0; sm < 2; sm++) {
        half4 gh[4][4];
#pragma unroll
        for (int ni = 0; ni < 4; ni++)
#pragma unroll
          for (int rg = 0; rg < 4; rg++)
#pragma unroll
            for (int mi = 0; mi < 4; mi++)
              gh[ni][rg][mi] = (_Float16)acc[sm][mi][ni][rg];
#pragma unroll
        for (int ni = 0; ni < 4; ni++)
#pragma unroll
          for (int rg = 0; rg < 4; rg++) {
            const int m2 = (fql * 4 + rg) * 32 + (ni & 1) * 16 + fr;
            *(half4*)&Gsh[sm][m2 * GSTR2 + wave * 16 + (ni >> 1) * 8 + fqh * 4] = gh[ni][rg];
          }
      }
      __syncthreads();   // B1: Gsh visible
      // ---- NS-phase: NS[m2][c] += G[m2][k'-window] * St3[c][same], both samples ----
#pragma unroll
      for (int sm = 0; sm < 2; sm++) {
#pragma unroll
        for (int kk = 0; kk < 2; kk++) {
          const half8 bs = *(const half8*)&St3[sm][fr * SSTR + cc * 64 + kk * 32 + fq * 8];
#pragma unroll
          for (int t = 0; t < 4; t++) {
            const half8 aa =
              *(const half8*)&Gsh[sm][((wave * 4 + t) * 16 + fr) * GSTR2 + kk * 32 + fq * 8];
            ns[sm][t] = __builtin_amdgcn_mfma_f32_16x16x32_f16(aa, bs, ns[sm][t], 0, 0, 0);
          }
        }
      }
      __syncthreads();   // B2: NS reads done before next cc overwrites Gsh
    }

    // epilogue: NS -> St3 (next step's B operand). m=(b,r): k_next = r*8+sigma(b)
    if (fr < 10) {
#pragma unroll
      for (int sm = 0; sm < 2; sm++)
#pragma unroll
        for (int t = 0; t < 4; t++)
#pragma unroll
          for (int rg = 0; rg < 4; rg++) {
            const int m = (wave * 4 + t) * 16 + fq * 4 + rg;
            const int b = m >> 5, r = m & 31;
            St3[sm][fr * SSTR + r * 8 + ((b & 1) * 4 + (b >> 1))] = (_Float16)ns[sm][t][rg];
          }
    }
    // next step's B1 orders these writes before any NS read
  }
  __syncthreads();

  // final: out[s,c] = sum_{a,l} St3[c][l*8+sigma(a)] * GN[a][s][l]
  {
    const int a = tid >> 5, l = tid & 31;
    const int kcol = l * 8 + ((a & 1) * 4 + (a >> 1));
#pragma unroll
    for (int sm = 0; sm < 2; sm++) {
      const float gn = GN[((size_t)a * 512 + s0 + sm) * 32 + l];
#pragma unroll
      for (int c = 0; c < 10; c++) {
        float v = gn * (float)St3[sm][c * SSTR + kcol];
#pragma unroll
        for (int o2 = 1; o2 < 64; o2 <<= 1) v += __shfl_xor(v, o2, 64);
        if (lane == 0) atomicAdd(&oc[sm][c], v);
      }
    }
    __syncthreads();
    if (tid < 20) out[(size_t)s0 * 10 + tid] = ((float*)oc)[tid];
  }
}

// ---------------- prep kernels (unchanged) ----------------
__global__ void prep_xh(const float* __restrict__ x, _Float16* __restrict__ xh) {
  const int idx = blockIdx.x * 256 + threadIdx.x;
  const int q = idx & 63, sp = idx >> 6;
  xh[idx] = (q < 48) ? (_Float16)x[sp * 48 + q] : (_Float16)0.f;
}

__global__ void prep_small(const float* __restrict__ cf, const float* __restrict__ cm,
                           const float* __restrict__ cl, const float* __restrict__ tf,
                           const float* __restrict__ tm, const float* __restrict__ tl,
                           _Float16* __restrict__ Ckt, _Float16* __restrict__ Akr,
                           _Float16* __restrict__ Bt0, _Float16* __restrict__ Btl) {
  const int idx = blockIdx.x * 256 + threadIdx.x;
  if (idx < 32768) {
    const int q = idx & 63;
    const int row = idx >> 6;
    float v = 0.f;
    if (q < 48) {
      if (row < 8) v = cf[q * 8 + row];
      else if (row < 392) {
        const int rr = row - 8;
        const int k = rr >> 6, ab = rr & 63, a = ab >> 3, b = ab & 7;
        v = cm[((k * 8 + a) * 48 + q) * 8 + b];
      } else if (row < 400) v = cl[(row - 392) * 48 + q];
    }
    Ckt[idx] = (_Float16)v;
  } else if (idx < 1409024) {
    const int i2 = idx - 32768;
    const int p = i2 % 224;
    const int lr = (i2 / 224) & 1023;
    const int k = i2 / (224 * 1024);
    const int l = lr >> 5, r = lr & 31;
    float v = 0.f;
    if (p < 196) v = tm[(((k * 32 + l) * 196) + p) * 32 + r];
    Akr[i2] = (_Float16)v;
  } else if (idx < 1495040) {
    const int i2 = idx - 1409024;
    const int p = i2 % 224;
    const int n = i2 / 224;
    float v = 0.f;
    if (n < 320 && p < 196) {
      const int r = n / 10, c = n % 10;
      v = tf[(c * 196 + p) * 32 + r];
    }
    Bt0[i2] = (_Float16)v;
  } else {
    const int i2 = idx - 1495040;
    const int p = i2 % 224;
    const int n = i2 / 224;
    float v = 0.f;
    if (n < 32 && p < 196) v = tl[n * 196 + p];
    Btl[i2] = (_Float16)v;
  }
}

__global__ void zero_pads(_Float16* __restrict__ Mt3, _Float16* __restrict__ MtF,
                          _Float16* __restrict__ MtL) {
  const int idx = blockIdx.x * 256 + threadIdx.x;
  if (idx < 196608) {
    const int s6 = idx >> 6, lane = idx & 63;
    const int4 z = {0, 0, 0, 0};
#pragma unroll
    for (int mi = 0; mi < 4; mi++)
      *(int4*)&Mt3[(((size_t)s6 * 28 + 24 + mi) * 64 + lane) * 8] = z;
  }
  if (idx < 4096) {
    _Float16* p = MtF + (size_t)idx * KP + 196;
    _Float16* q = MtL + (size_t)idx * KP + 196;
#pragma unroll
    for (int j = 0; j < 28; j++) { p[j] = (_Float16)0.f; q[j] = (_Float16)0.f; }
  }
}

extern "C" void kernel_launch(void* const* d_in, const int* in_sizes, int n_in,
                              void* d_out, int out_size, void* d_ws, size_t ws_size,
                              hipStream_t stream)
{
  const float* x  = (const float*)d_in[0];
  const float* cf = (const float*)d_in[1];
  const float* cm = (const float*)d_in[2];
  const float* cl = (const float*)d_in[3];
  const float* tf = (const float*)d_in[4];
  const float* tm = (const float*)d_in[5];
  const float* tl = (const float*)d_in[6];
  float* out = (float*)d_out;

  char* w = (char*)d_ws;
  auto alloc = [&](size_t bytes) { char* p = w; w += (bytes + 255) & ~(size_t)255; return p; };
  _Float16* xh  = (_Float16*)alloc(100352ull * 64 * 2);
  _Float16* Ckt = (_Float16*)alloc(512ull * 64 * 2);
  _Float16* Mt3 = (_Float16*)alloc(512ull * 6 * SLICE * 2);
  _Float16* MtF = (_Float16*)alloc(8ull * 512 * KP * 2);
  _Float16* MtL = (_Float16*)alloc(8ull * 512 * KP * 2);
  _Float16* Akr = (_Float16*)alloc(6ull * 1024 * KP * 2);
  _Float16* Bt0 = (_Float16*)alloc(384ull * KP * 2);
  _Float16* Btl = (_Float16*)alloc(128ull * KP * 2);
  float* stA    = (float*)alloc(512ull * 2560 * 4);
  float* GN     = (float*)alloc(4096ull * 32 * 4);
  (void)ws_size; (void)in_sizes; (void)n_in; (void)out_size;

  prep_xh   <<<25088, 256, 0, stream>>>(x, xh);
  prep_small<<< 5952, 256, 0, stream>>>(cf, cm, cl, tf, tm, tl, Ckt, Akr, Bt0, Btl);
  zero_pads <<<  768, 256, 0, stream>>>(Mt3, MtF, MtL);

  gemm_mfma<QP, 0><<<dim3(784, 4), 256, 0, stream>>>(Ckt, xh, Mt3, MtF, MtL);
  gemm_mfma<KP, 2><<<dim3(3, 32), 256, 0, stream>>>(MtF, Bt0, stA, nullptr, nullptr);
  gemm_mfma<KP, 3><<<dim3(1, 32), 256, 0, stream>>>(MtL, Btl, GN, nullptr, nullptr);

  chain_kernel<<<256, 256, 0, stream>>>(Mt3, Akr, stA, GN, out);
}

// Round 9
// 276.487 us; speedup vs baseline: 1.7954x; 1.7954x over previous
//
#include <hip/hip_runtime.h>

// TensorConvolutionTrainLayer: S=512,P=196,Q=48,CB=8,R=32,C=10,N=8
// R9: R8 (3 blocks/CU, h-split A, ni=2/cc=8) with the bfX pipelining hazard
// fixed: consume current window into locals BEFORE prefetch overwrites the
// slots (R8 read clobbered fragments -> absmax 15968).

typedef _Float16 half8 __attribute__((ext_vector_type(8)));
typedef _Float16 half4 __attribute__((ext_vector_type(4)));
typedef float floatx4 __attribute__((ext_vector_type(4)));

#define KP 224      // P padded to 7*32
#define QP 64       // Q padded to 2*32
#define GSTR 40     // Gsh row stride (halfs): 80 B (R4-proven)
#define SSTR 264    // St3 row stride (halfs)
#define SLICE 14336 // per-(s,k) A slice: 28 frags * 64 lanes * 8 halfs

__device__ __forceinline__ void gld_lds16(const void* g, void* l) {
  __builtin_amdgcn_global_load_lds((const __attribute__((address_space(1))) void*)g,
                                   (__attribute__((address_space(3))) void*)l, 16, 0, 0);
}

// ---------------- generic MFMA GEMM (unchanged) ----------------
template<int K, int MODE>
__global__ __launch_bounds__(256)
void gemm_mfma(const _Float16* __restrict__ A, const _Float16* __restrict__ Bt,
               void* __restrict__ out0, void* __restrict__ out1, void* __restrict__ out2)
{
  __shared__ __align__(16) _Float16 Ash[128 * 32];
  __shared__ __align__(16) _Float16 Bsh[128 * 32];
  const int tid  = threadIdx.x;
  const int wave = tid >> 6;
  const int lane = tid & 63;
  const int m0 = blockIdx.y * 128;
  const int n0 = blockIdx.x * 128;
  const int wm = (wave >> 1) * 64;
  const int wn = (wave & 1) * 64;
  const int fr = lane & 15;
  const int fq = lane >> 4;

  floatx4 acc[4][4] = {};

  for (int kt = 0; kt < K; kt += 32) {
    __syncthreads();
#pragma unroll
    for (int j = 0; j < 2; j++) {
      const int c   = j * 256 + tid;
      const int row = c >> 2;
      const int ko  = (c & 3) * 8;
      gld_lds16(A  + (size_t)(m0 + row) * K + kt + ko,
                (char*)Ash + (size_t)(j * 256 + wave * 64) * 16);
      gld_lds16(Bt + (size_t)(n0 + row) * K + kt + ko,
                (char*)Bsh + (size_t)(j * 256 + wave * 64) * 16);
    }
    __syncthreads();
    half8 af[4], bf[4];
#pragma unroll
    for (int i = 0; i < 4; i++)
      af[i] = *(const half8*)&Ash[(wm + i * 16 + fr) * 32 + fq * 8];
#pragma unroll
    for (int i = 0; i < 4; i++)
      bf[i] = *(const half8*)&Bsh[(wn + i * 16 + fr) * 32 + fq * 8];
#pragma unroll
    for (int i = 0; i < 4; i++)
#pragma unroll
      for (int j = 0; j < 4; j++)
        acc[i][j] = __builtin_amdgcn_mfma_f32_16x16x32_f16(af[i], bf[j], acc[i][j], 0, 0, 0);
  }

#pragma unroll
  for (int i = 0; i < 4; i++) {
#pragma unroll
    for (int j = 0; j < 4; j++) {
#pragma unroll
      for (int r = 0; r < 4; r++) {
        const int m = m0 + wm + i * 16 + fq * 4 + r;
        const int n = n0 + wn + j * 16 + fr;
        const float v = acc[i][j][r];
        if constexpr (MODE == 0) {
          const unsigned s = (unsigned)n / 196u;
          const unsigned p = (unsigned)n - s * 196u;
          if (m < 8) {
            ((_Float16*)out1)[((size_t)m * 512 + s) * KP + p] = (_Float16)v;
          } else if (m < 392) {
            const int mm = m - 8;
            const size_t idx =
              ((((size_t)s * 6 + (mm >> 6)) * 28 + (p >> 5) * 4 + ((mm & 63) >> 4)) * 64
               + ((p >> 3) & 3) * 16 + (mm & 15)) * 8 + (p & 7);
            ((_Float16*)out0)[idx] = (_Float16)v;
          } else if (m < 400) {
            ((_Float16*)out2)[((size_t)(m - 392) * 512 + s) * KP + p] = (_Float16)v;
          }
        } else if constexpr (MODE == 2) {
          if (n < 320)
            ((float*)out0)[(size_t)(m & 511) * 2560 + (m >> 9) * 320 + n] = v;
        } else {
          if (n < 32)
            ((float*)out0)[(size_t)m * 32 + n] = v;
        }
      }
    }
  }
}

// ---------------- fused chain kernel: 3 blocks/CU, h-split A ----------------
__global__ __launch_bounds__(256, 3)
void chain_kernel(const _Float16* __restrict__ Mt3, const _Float16* __restrict__ Akr,
                  const float* __restrict__ St0, const float* __restrict__ GN,
                  float* __restrict__ out)
{
  __shared__ __align__(16) _Float16 Ash[16 * 512];   // 16384 B (one h-region)
  __shared__ __align__(16) _Float16 Gsh[256 * GSTR]; // 20480 B
  __shared__ __align__(16) _Float16 St3[16 * SSTR];  // 8448 B
  __shared__ float oc[10];

  const int tid  = threadIdx.x;
  const int wave = tid >> 6;
  const int lane = tid & 63;
  const int s    = blockIdx.x;
  const int fr   = lane & 15;
  const int fq   = lane >> 4;
  const int fqh  = fq >> 1;
  const int fql  = fq & 1;

  // init: St3[c][r*8+sigma(b)] from St0[s][b*320+r*10+c]; tid=(b,r)
  {
    const int b = tid >> 5, r = tid & 31;
    const int kcol = r * 8 + ((b & 1) * 4 + (b >> 1));
    const float* src = St0 + (size_t)s * 2560 + (size_t)tid * 10;
#pragma unroll
    for (int c = 0; c < 10; c++) St3[c * SSTR + kcol] = (_Float16)src[c];
    if (tid < 10) oc[tid] = 0.f;
  }
  // stage h0 of step 0 (frags 0..15 = 1024 chunks, 4 per thread)
  {
    const _Float16* base = Mt3 + (size_t)s * 6 * SLICE;
#pragma unroll
    for (int it = 0; it < 4; it++)
      gld_lds16(base + (size_t)(it * 256 + tid) * 8,
                (char*)Ash + (size_t)(it * 256 + wave * 64) * 16);
  }
  // preload bfX = (k0,h0,cc0,kt0) window fragments
  half8 bfX[2];
  {
    const _Float16* Bb = Akr + (size_t)(wave * 32) * KP;
#pragma unroll
    for (int ni = 0; ni < 2; ni++)
      bfX[ni] = *(const half8*)(Bb + (size_t)(ni * 16 + fr) * KP + fq * 8);
  }
  __syncthreads();   // Ash-h0 (vmcnt drained) + St3 visible

  for (int k = 0; k < 6; k++) {
    floatx4 ns[4] = {};
    const _Float16* Bk = Akr + (size_t)k * 1024 * KP;

#pragma unroll
    for (int h = 0; h < 2; h++) {
      const int KT = h ? 3 : 4;
#pragma unroll
      for (int cc = 0; cc < 8; cc++) {
        const _Float16* Bb = Bk + (size_t)(cc * 128 + wave * 32) * KP + h * 128;
        // next-body B base (deref guarded by lastBody)
        const _Float16* Bn;
        if (cc < 7)       Bn = Bk + (size_t)((cc + 1) * 128 + wave * 32) * KP + h * 128;
        else if (h == 0)  Bn = Bk + (size_t)(wave * 32) * KP + 128;
        else              Bn = Akr + (size_t)(k < 5 ? k + 1 : 5) * 1024 * KP
                               + (size_t)(wave * 32) * KP;
        const bool lastBody = (h == 1 && cc == 7 && k == 5);

        // ---- G-phase: partial G over this h's kt windows ----
        floatx4 acc[4][2] = {};
#pragma unroll
        for (int kt = 0; kt < KT; kt++) {
          // consume current window into SSA locals BEFORE overwriting bfX
          const half8 b0 = bfX[0];
          const half8 b1 = bfX[1];
          if (kt < KT - 1) {          // prefetch next kt window
#pragma unroll
            for (int ni = 0; ni < 2; ni++)
              bfX[ni] = *(const half8*)(Bb + (size_t)(ni * 16 + fr) * KP
                                        + (kt + 1) * 32 + fq * 8);
          } else if (!lastBody) {     // prefetch next body's kt0 window
#pragma unroll
            for (int ni = 0; ni < 2; ni++)
              bfX[ni] = *(const half8*)(Bn + (size_t)(ni * 16 + fr) * KP + fq * 8);
          }
          half8 af[4];
#pragma unroll
          for (int mi = 0; mi < 4; mi++)   // lane-contiguous, conflict-free
            af[mi] = *(const half8*)&Ash[((kt * 4 + mi) * 64 + lane) * 8];
#pragma unroll
          for (int mi = 0; mi < 4; mi++) {
            acc[mi][0] = __builtin_amdgcn_mfma_f32_16x16x32_f16(af[mi], b0, acc[mi][0], 0, 0, 0);
            acc[mi][1] = __builtin_amdgcn_mfma_f32_16x16x32_f16(af[mi], b1, acc[mi][1], 0, 0, 0);
          }
        }
        // cvt + write Gsh: row m2=(b,r), k' = wave*8 + fqh*4 + mi  (R4 mapping)
#pragma unroll
        for (int ni = 0; ni < 2; ni++)
#pragma unroll
          for (int rg = 0; rg < 4; rg++) {
            half4 gh;
#pragma unroll
            for (int mi = 0; mi < 4; mi++) gh[mi] = (_Float16)acc[mi][ni][rg];
            const int m2 = (fql * 4 + rg) * 32 + ni * 16 + fr;
            *(half4*)&Gsh[m2 * GSTR + wave * 8 + fqh * 4] = gh;
          }
        __syncthreads();   // bar1: Gsh visible; all waves past this h's Ash reads (cc==7)
        if (h == 0 && cc == 7) {   // stage h1 (frags 16..27: 768 chunks)
          const _Float16* base = Mt3 + ((size_t)s * 6 + k) * SLICE + 16 * 512;
#pragma unroll
          for (int it = 0; it < 3; it++)
            gld_lds16(base + (size_t)(it * 256 + tid) * 8,
                      (char*)Ash + (size_t)(it * 256 + wave * 64) * 16);
        }
        if (h == 1 && cc == 7 && k < 5) {  // stage next step's h0
          const _Float16* base = Mt3 + ((size_t)s * 6 + k + 1) * SLICE;
#pragma unroll
          for (int it = 0; it < 4; it++)
            gld_lds16(base + (size_t)(it * 256 + tid) * 8,
                      (char*)Ash + (size_t)(it * 256 + wave * 64) * 16);
        }
        // ---- NS-phase: ns += G_partial * St3 (k-window = cc*32) ----
        {
          const half8 bs = *(const half8*)&St3[fr * SSTR + cc * 32 + fq * 8];
#pragma unroll
          for (int t = 0; t < 4; t++) {
            const half8 aa =
              *(const half8*)&Gsh[((wave * 4 + t) * 16 + fr) * GSTR + fq * 8];
            ns[t] = __builtin_amdgcn_mfma_f32_16x16x32_f16(aa, bs, ns[t], 0, 0, 0);
          }
        }
        __syncthreads();   // bar2: NS reads done (Gsh free) + staged Ash drained
      }
    }

    // epilogue: NS -> St3 (next step's B operand). m=(b,r): k_next = r*8+sigma(b)
    if (fr < 10) {
#pragma unroll
      for (int t = 0; t < 4; t++)
#pragma unroll
        for (int rg = 0; rg < 4; rg++) {
          const int m = (wave * 4 + t) * 16 + fq * 4 + rg;
          const int b = m >> 5, r = m & 31;
          St3[fr * SSTR + r * 8 + ((b & 1) * 4 + (b >> 1))] = (_Float16)ns[t][rg];
        }
    }
    // next step's bar1 orders these writes before any NS read
  }
  __syncthreads();

  // final: out[s,c] = sum_{a,l} St3[c][l*8+sigma(a)] * GN[a][s][l]
  {
    const int a = tid >> 5, l = tid & 31;
    const float gn = GN[((size_t)a * 512 + s) * 32 + l];
    const int kcol = l * 8 + ((a & 1) * 4 + (a >> 1));
#pragma unroll
    for (int c = 0; c < 10; c++) {
      float v = gn * (float)St3[c * SSTR + kcol];
#pragma unroll
      for (int o2 = 1; o2 < 64; o2 <<= 1) v += __shfl_xor(v, o2, 64);
      if (lane == 0) atomicAdd(&oc[c], v);
    }
    __syncthreads();
    if (tid < 10) out[(size_t)s * 10 + tid] = oc[tid];
  }
}

// ---------------- prep kernels (unchanged) ----------------
__global__ void prep_xh(const float* __restrict__ x, _Float16* __restrict__ xh) {
  const int idx = blockIdx.x * 256 + threadIdx.x;
  const int q = idx & 63, sp = idx >> 6;
  xh[idx] = (q < 48) ? (_Float16)x[sp * 48 + q] : (_Float16)0.f;
}

__global__ void prep_small(const float* __restrict__ cf, const float* __restrict__ cm,
                           const float* __restrict__ cl, const float* __restrict__ tf,
                           const float* __restrict__ tm, const float* __restrict__ tl,
                           _Float16* __restrict__ Ckt, _Float16* __restrict__ Akr,
                           _Float16* __restrict__ Bt0, _Float16* __restrict__ Btl) {
  const int idx = blockIdx.x * 256 + threadIdx.x;
  if (idx < 32768) {
    const int q = idx & 63;
    const int row = idx >> 6;
    float v = 0.f;
    if (q < 48) {
      if (row < 8) v = cf[q * 8 + row];
      else if (row < 392) {
        const int rr = row - 8;
        const int k = rr >> 6, ab = rr & 63, a = ab >> 3, b = ab & 7;
        v = cm[((k * 8 + a) * 48 + q) * 8 + b];
      } else if (row < 400) v = cl[(row - 392) * 48 + q];
    }
    Ckt[idx] = (_Float16)v;
  } else if (idx < 1409024) {
    const int i2 = idx - 32768;
    const int p = i2 % 224;
    const int lr = (i2 / 224) & 1023;
    const int k = i2 / (224 * 1024);
    const int l = lr >> 5, r = lr & 31;
    float v = 0.f;
    if (p < 196) v = tm[(((k * 32 + l) * 196) + p) * 32 + r];
    Akr[i2] = (_Float16)v;
  } else if (idx < 1495040) {
    const int i2 = idx - 1409024;
    const int p = i2 % 224;
    const int n = i2 / 224;
    float v = 0.f;
    if (n < 320 && p < 196) {
      const int r = n / 10, c = n % 10;
      v = tf[(c * 196 + p) * 32 + r];
    }
    Bt0[i2] = (_Float16)v;
  } else {
    const int i2 = idx - 1495040;
    const int p = i2 % 224;
    const int n = i2 / 224;
    float v = 0.f;
    if (n < 32 && p < 196) v = tl[n * 196 + p];
    Btl[i2] = (_Float16)v;
  }
}

__global__ void zero_pads(_Float16* __restrict__ Mt3, _Float16* __restrict__ MtF,
                          _Float16* __restrict__ MtL) {
  const int idx = blockIdx.x * 256 + threadIdx.x;
  if (idx < 196608) {
    const int s6 = idx >> 6, lane = idx & 63;
    const int4 z = {0, 0, 0, 0};
#pragma unroll
    for (int mi = 0; mi < 4; mi++)
      *(int4*)&Mt3[(((size_t)s6 * 28 + 24 + mi) * 64 + lane) * 8] = z;
  }
  if (idx < 4096) {
    _Float16* p = MtF + (size_t)idx * KP + 196;
    _Float16* q = MtL + (size_t)idx * KP + 196;
#pragma unroll
    for (int j = 0; j < 28; j++) { p[j] = (_Float16)0.f; q[j] = (_Float16)0.f; }
  }
}

extern "C" void kernel_launch(void* const* d_in, const int* in_sizes, int n_in,
                              void* d_out, int out_size, void* d_ws, size_t ws_size,
                              hipStream_t stream)
{
  const float* x  = (const float*)d_in[0];
  const float* cf = (const float*)d_in[1];
  const float* cm = (const float*)d_in[2];
  const float* cl = (const float*)d_in[3];
  const float* tf = (const float*)d_in[4];
  const float* tm = (const float*)d_in[5];
  const float* tl = (const float*)d_in[6];
  float* out = (float*)d_out;

  char* w = (char*)d_ws;
  auto alloc = [&](size_t bytes) { char* p = w; w += (bytes + 255) & ~(size_t)255; return p; };
  _Float16* xh  = (_Float16*)alloc(100352ull * 64 * 2);
  _Float16* Ckt = (_Float16*)alloc(512ull * 64 * 2);
  _Float16* Mt3 = (_Float16*)alloc(512ull * 6 * SLICE * 2);
  _Float16* MtF = (_Float16*)alloc(8ull * 512 * KP * 2);
  _Float16* MtL = (_Float16*)alloc(8ull * 512 * KP * 2);
  _Float16* Akr = (_Float16*)alloc(6ull * 1024 * KP * 2);
  _Float16* Bt0 = (_Float16*)alloc(384ull * KP * 2);
  _Float16* Btl = (_Float16*)alloc(128ull * KP * 2);
  float* stA    = (float*)alloc(512ull * 2560 * 4);
  float* GN     = (float*)alloc(4096ull * 32 * 4);
  (void)ws_size; (void)in_sizes; (void)n_in; (void)out_size;

  prep_xh   <<<25088, 256, 0, stream>>>(x, xh);
  prep_small<<< 5952, 256, 0, stream>>>(cf, cm, cl, tf, tm, tl, Ckt, Akr, Bt0, Btl);
  zero_pads <<<  768, 256, 0, stream>>>(Mt3, MtF, MtL);

  gemm_mfma<QP, 0><<<dim3(784, 4), 256, 0, stream>>>(Ckt, xh, Mt3, MtF, MtL);
  gemm_mfma<KP, 2><<<dim3(3, 32), 256, 0, stream>>>(MtF, Bt0, stA, nullptr, nullptr);
  gemm_mfma<KP, 3><<<dim3(1, 32), 256, 0, stream>>>(MtL, Btl, GN, nullptr, nullptr);

  chain_kernel<<<512, 256, 0, stream>>>(Mt3, Akr, stA, GN, out);
}